// Round 5
// baseline (485.572 us; speedup 1.0000x reference)
//
#include <hip/hip_runtime.h>

#define RES 128
#define RES_V 129
#define N_VOX 400000

constexpr int N_VERTS = RES_V * RES_V * RES_V;   // 2146689
constexpr int N_CELLS = RES * RES * RES;         // 2097152
constexpr long VOUT_WORDS = (long)N_VERTS * 10;  // 21466890
constexpr long OUTW_WORDS = (long)N_CELLS * 21;  // 44040192
constexpr int SCAN_BLOCKS = 512;                 // N_CELLS / 4096
constexpr float SDF_BIAS = -1.0f / 128.0f;
constexpr float DEFORM_SCALE = (float)((1.0 - 1e-8) / 256.0);
constexpr float INV_RES = 1.0f / 128.0f;
constexpr int CROWS = 192;  // staged voxel-row capacity per block (mean 139, sd ~11)

// --- K0: zero the cell histogram ---
__global__ void init_counts(unsigned int* __restrict__ counts)
{
    int t = blockIdx.x * blockDim.x + threadIdx.x;
    if (t < N_CELLS) counts[t] = 0u;
}

// --- K1: per-voxel cell histogram ---
__global__ void count_kernel(const int* __restrict__ coords,
                             unsigned int* __restrict__ counts)
{
    int n = blockIdx.x * blockDim.x + threadIdx.x;
    if (n >= N_VOX) return;
    int cx = coords[n * 3 + 0];
    int cy = coords[n * 3 + 1];
    int cz = coords[n * 3 + 2];
    int cid = (cx * RES + cy) * RES + cz;
    atomicAdd(counts + cid, 1u);
}

// --- K2: block-local exclusive scan (4096 elems / block) -> starts(local) ---
__global__ void scan1_kernel(const unsigned int* __restrict__ counts,
                             unsigned int* __restrict__ starts,
                             unsigned int* __restrict__ blocksums)
{
    __shared__ unsigned int part[256];
    int b = blockIdx.x, t = threadIdx.x;
    long base = (long)b * 4096 + (long)t * 16;
    unsigned int v[16], s = 0;
#pragma unroll
    for (int i = 0; i < 16; ++i) { v[i] = counts[base + i]; s += v[i]; }
    part[t] = s;
    __syncthreads();
    for (int off = 1; off < 256; off <<= 1) {
        unsigned int x = (t >= off) ? part[t - off] : 0u;
        __syncthreads();
        part[t] += x;
        __syncthreads();
    }
    unsigned int excl = (t == 0) ? 0u : part[t - 1];
    if (t == 255) blocksums[b] = part[255];
    unsigned int run = excl;
#pragma unroll
    for (int i = 0; i < 16; ++i) { starts[base + i] = run; run += v[i]; }
}

// --- K3: exclusive scan of the 512 block sums (single block) ---
__global__ void scan2_kernel(unsigned int* __restrict__ blocksums)
{
    __shared__ unsigned int sh[SCAN_BLOCKS];
    int t = threadIdx.x;
    sh[t] = blocksums[t];
    __syncthreads();
    for (int off = 1; off < SCAN_BLOCKS; off <<= 1) {
        unsigned int x = (t >= off) ? sh[t - off] : 0u;
        __syncthreads();
        sh[t] += x;
        __syncthreads();
    }
    blocksums[t] = (t == 0) ? 0u : sh[t - 1];
}

// --- K4: globalize starts, copy to fill cursors, write sentinel ---
__global__ void fixup_kernel(unsigned int* __restrict__ starts,
                             unsigned int* __restrict__ cursors,
                             const unsigned int* __restrict__ blocksums)
{
    int t = blockIdx.x * blockDim.x + threadIdx.x;
    if (t >= N_CELLS) return;
    unsigned int g = starts[t] + blocksums[t >> 12];
    starts[t] = g;
    cursors[t] = g;
    if (t == 0) starts[N_CELLS] = (unsigned int)N_VOX;
}

// --- K5: fill CSR list ---
__global__ void fill_kernel(const int* __restrict__ coords,
                            unsigned int* __restrict__ cursors,
                            unsigned int* __restrict__ list)
{
    int n = blockIdx.x * blockDim.x + threadIdx.x;
    if (n >= N_VOX) return;
    int cx = coords[n * 3 + 0];
    int cy = coords[n * 3 + 1];
    int cz = coords[n * 3 + 2];
    int cid = (cx * RES + cy) * RES + cz;
    unsigned int slot = atomicAdd(cursors + cid, 1u);
    list[slot] = (unsigned int)n;
}

// --- K6: LDS-staged gather ---
// Block = 8x8x8 vertex tile. Stage A: census of the 9^3 cell region (CSR) +
// block scan to pack voxel rows. Stage B: coalesced copy of the 80 needed
// floats/row into LDS. Stage C: per-vertex gather entirely from LDS.
// Overflow (>CROWS rows, ~never) falls back to global gather per cell.
__global__ void gather_staged(const float* __restrict__ feats,
                              const unsigned int* __restrict__ starts,
                              const unsigned int* __restrict__ list,
                              float* __restrict__ vout)
{
    __shared__ float srow[CROWS * 81];           // 81-stride: bank spread
    __shared__ unsigned int cell_s[729];
    __shared__ unsigned short cell_cnt[729];
    __shared__ unsigned short cell_rs[729];
    __shared__ unsigned int rown[CROWS];
    __shared__ unsigned int tsum[256];
    __shared__ unsigned int sh_total;

    int tid = threadIdx.x;
    int vx0 = blockIdx.z * 8, vy0 = blockIdx.y * 8, vz0 = blockIdx.x * 8;

    for (int r = tid; r < CROWS; r += 256) rown[r] = 0xFFFFFFFFu;

    // --- stage A: census ---
    int c0 = tid * 3;
    unsigned int mysum = 0;
#pragma unroll
    for (int k = 0; k < 3; ++k) {
        int ci = c0 + k;
        if (ci < 729) {
            unsigned int cnt = 0, s = 0;
            int ix = ci / 81, iy = (ci / 9) % 9, iz = ci % 9;
            int cx = vx0 - 1 + ix, cy = vy0 - 1 + iy, cz = vz0 - 1 + iz;
            if ((unsigned)cx < RES && (unsigned)cy < RES && (unsigned)cz < RES) {
                int cid = (cx * RES + cy) * RES + cz;
                s = starts[cid];
                cnt = starts[cid + 1] - s;
            }
            cell_s[ci] = s;
            cell_cnt[ci] = (unsigned short)cnt;
            mysum += cnt;
        }
    }
    tsum[tid] = mysum;
    __syncthreads();
    for (int off = 1; off < 256; off <<= 1) {
        unsigned int x = (tid >= off) ? tsum[tid - off] : 0u;
        __syncthreads();
        tsum[tid] += x;
        __syncthreads();
    }
    if (tid == 255) sh_total = tsum[255];
    unsigned int run = (tid == 0) ? 0u : tsum[tid - 1];
#pragma unroll
    for (int k = 0; k < 3; ++k) {
        int ci = c0 + k;
        if (ci < 729) {
            unsigned int cnt = cell_cnt[ci];
            unsigned int rs = run;
            run += cnt;
            if (cnt > 0u && rs + cnt <= (unsigned)CROWS) {
                cell_rs[ci] = (unsigned short)rs;
                unsigned int s = cell_s[ci];
                for (unsigned int j = 0; j < cnt; ++j) rown[rs + j] = list[s + j];
            } else {
                cell_rs[ci] = 0xFFFFu;   // unstaged (empty or overflow)
            }
        }
    }
    __syncthreads();

    // --- stage B: coalesced row copy feats -> LDS ---
    int bound = (int)min(sh_total, (unsigned)CROWS);
    for (int idx = tid; idx < bound * 80; idx += 256) {
        int r = idx / 80;
        int j = idx - r * 80;
        unsigned int n = rown[r];
        if (n != 0xFFFFFFFFu)
            srow[r * 81 + j] = feats[(long)n * 101 + (j < 32 ? j : j + 21)];
    }
    __syncthreads();

    // --- stage C: per-vertex gather from LDS ---
    for (int h = 0; h < 2; ++h) {
        int lv = tid + h * 256;
        int lx = lv >> 6, ly = (lv >> 3) & 7, lz = lv & 7;
        int x = vx0 + lx, y = vy0 + ly, z = vz0 + lz;
        if (x >= RES_V || y >= RES_V || z >= RES_V) continue;

        float sums[10];
#pragma unroll
        for (int j = 0; j < 10; ++j) sums[j] = 0.0f;
        int cnt = 0;

#pragma unroll
        for (int dz = 0; dz < 2; ++dz) {
            int cz = z - dz;
            if ((unsigned)cz >= RES) continue;
#pragma unroll
            for (int dy = 0; dy < 2; ++dy) {
                int cy = y - dy;
                if ((unsigned)cy >= RES) continue;
#pragma unroll
                for (int dx = 0; dx < 2; ++dx) {
                    int cx = x - dx;
                    if ((unsigned)cx >= RES) continue;
                    int ci = ((lx + 1 - dx) * 9 + (ly + 1 - dy)) * 9 + (lz + 1 - dz);
                    int cc = cell_cnt[ci];
                    if (!cc) continue;
                    int c = dx + 2 * dy + 4 * dz;
                    unsigned int rs = cell_rs[ci];
                    if (rs != 0xFFFFu) {
                        for (int r = (int)rs; r < (int)rs + cc; ++r) {
                            const float* b = srow + r * 81;
                            sums[0] += b[c];
#pragma unroll
                            for (int k = 0; k < 3; ++k) sums[1 + k] += b[8 + 3 * c + k];
#pragma unroll
                            for (int k = 0; k < 6; ++k) sums[4 + k] += b[32 + 6 * c + k];
                        }
                    } else {
                        unsigned int s = cell_s[ci];
                        for (unsigned int i = s; i < s + (unsigned)cc; ++i) {
                            const float* f = feats + (long)list[i] * 101;
                            sums[0] += f[c];
#pragma unroll
                            for (int k = 0; k < 3; ++k) sums[1 + k] += f[8 + 3 * c + k];
#pragma unroll
                            for (int k = 0; k < 6; ++k) sums[4 + k] += f[53 + 6 * c + k];
                        }
                    }
                    cnt += cc;
                }
            }
        }

        float fc = (float)cnt;
        float inv = 1.0f / fmaxf(fc, 1.0f);
        float o[10];
        o[0] = (float)x * INV_RES - 0.5f + DEFORM_SCALE * tanhf(sums[1] * inv);
        o[1] = (float)y * INV_RES - 0.5f + DEFORM_SCALE * tanhf(sums[2] * inv);
        o[2] = (float)z * INV_RES - 0.5f + DEFORM_SCALE * tanhf(sums[3] * inv);
        o[3] = (sums[0] + fc * SDF_BIAS) * inv;
#pragma unroll
        for (int j = 0; j < 6; ++j) o[4 + j] = sums[4 + j] * inv;

        int vid = (x * RES_V + y) * RES_V + z;
        float* p = vout + (long)vid * 10;
#pragma unroll
        for (int j = 0; j < 10; ++j) p[j] = o[j];
    }
}

// --- K7: weights grid; last-write-wins = max voxel id in the cell's CSR list ---
__global__ void weights_fill(const float* __restrict__ feats,
                             const unsigned int* __restrict__ starts,
                             const unsigned int* __restrict__ list,
                             float* __restrict__ outw)
{
    long t = (long)blockIdx.x * blockDim.x + threadIdx.x;
    if (t >= OUTW_WORDS) return;
    int cid = (int)(t / 21);
    int j = (int)(t - (long)cid * 21);
    unsigned int s = starts[cid], e = starts[cid + 1];
    float val = 0.0f;
    if (e > s) {
        unsigned int li = 0u;
        for (unsigned int i = s; i < e; ++i) li = max(li, list[i]);
        val = feats[(long)li * 101 + 32 + j];
    }
    outw[t] = val;
}

extern "C" void kernel_launch(void* const* d_in, const int* in_sizes, int n_in,
                              void* d_out, int out_size, void* d_ws, size_t ws_size,
                              hipStream_t stream) {
    const int* coords = (const int*)d_in[0];
    const float* feats = (const float*)d_in[1];
    float* out = (float*)d_out;
    float* vout = out;                          // [N_VERTS*10]
    float* outw = out + VOUT_WORDS;             // [N_CELLS*21]

    // d_ws (~10 MB): starts[N_CELLS+1], list[N_VOX], blocksums[512]
    unsigned int* starts = (unsigned int*)d_ws;
    unsigned int* list = starts + (N_CELLS + 1);
    unsigned int* blocksums = list + N_VOX;

    // counts/cursors live in the TAIL of outw: dead after fill_kernel, which
    // runs strictly before weights_fill overwrites outw.
    unsigned int* counts = (unsigned int*)(outw + (OUTW_WORDS - N_CELLS - 16));

    init_counts<<<(N_CELLS + 255) / 256, 256, 0, stream>>>(counts);
    count_kernel<<<(N_VOX + 255) / 256, 256, 0, stream>>>(coords, counts);
    scan1_kernel<<<SCAN_BLOCKS, 256, 0, stream>>>(counts, starts, blocksums);
    scan2_kernel<<<1, SCAN_BLOCKS, 0, stream>>>(blocksums);
    fixup_kernel<<<(N_CELLS + 255) / 256, 256, 0, stream>>>(starts, counts, blocksums);
    fill_kernel<<<(N_VOX + 255) / 256, 256, 0, stream>>>(coords, counts, list);
    {
        dim3 grid(17, 17, 17), block(256, 1, 1);
        gather_staged<<<grid, block, 0, stream>>>(feats, starts, list, vout);
    }
    {
        long total = OUTW_WORDS;
        weights_fill<<<(int)((total + 255) / 256), 256, 0, stream>>>(feats, starts, list, outw);
    }
}

// Round 6
// 400.224 us; speedup vs baseline: 1.2133x; 1.2133x over previous
//
#include <hip/hip_runtime.h>

#define RES 128
#define RES_V 129
#define N_VOX 400000

constexpr int N_VERTS = RES_V * RES_V * RES_V;   // 2146689
constexpr int N_CELLS = RES * RES * RES;         // 2097152
constexpr long VOUT_WORDS = (long)N_VERTS * 10;  // 21466890
constexpr long OUTW_WORDS = (long)N_CELLS * 21;  // 44040192
constexpr int SCAN_BLOCKS = 512;                 // N_CELLS / 4096
constexpr float SDF_BIAS = -1.0f / 128.0f;
constexpr float DEFORM_SCALE = (float)((1.0 - 1e-8) / 256.0);
constexpr float INV_RES = 1.0f / 128.0f;

// --- K0: zero the cell histogram ---
__global__ void init_counts(unsigned int* __restrict__ counts)
{
    int t = blockIdx.x * blockDim.x + threadIdx.x;
    if (t < N_CELLS) counts[t] = 0u;
}

// --- K1: per-voxel cell histogram ---
__global__ void count_kernel(const int* __restrict__ coords,
                             unsigned int* __restrict__ counts)
{
    int n = blockIdx.x * blockDim.x + threadIdx.x;
    if (n >= N_VOX) return;
    int cx = coords[n * 3 + 0];
    int cy = coords[n * 3 + 1];
    int cz = coords[n * 3 + 2];
    int cid = (cx * RES + cy) * RES + cz;
    atomicAdd(counts + cid, 1u);
}

// --- K2: block-local exclusive scan (4096 elems / block) -> starts(local) ---
__global__ void scan1_kernel(const unsigned int* __restrict__ counts,
                             unsigned int* __restrict__ starts,
                             unsigned int* __restrict__ blocksums)
{
    __shared__ unsigned int part[256];
    int b = blockIdx.x, t = threadIdx.x;
    long base = (long)b * 4096 + (long)t * 16;
    unsigned int v[16], s = 0;
#pragma unroll
    for (int i = 0; i < 16; ++i) { v[i] = counts[base + i]; s += v[i]; }
    part[t] = s;
    __syncthreads();
    for (int off = 1; off < 256; off <<= 1) {
        unsigned int x = (t >= off) ? part[t - off] : 0u;
        __syncthreads();
        part[t] += x;
        __syncthreads();
    }
    unsigned int excl = (t == 0) ? 0u : part[t - 1];
    if (t == 255) blocksums[b] = part[255];
    unsigned int run = excl;
#pragma unroll
    for (int i = 0; i < 16; ++i) { starts[base + i] = run; run += v[i]; }
}

// --- K3: exclusive scan of the 512 block sums (single block) ---
__global__ void scan2_kernel(unsigned int* __restrict__ blocksums)
{
    __shared__ unsigned int sh[SCAN_BLOCKS];
    int t = threadIdx.x;
    sh[t] = blocksums[t];
    __syncthreads();
    for (int off = 1; off < SCAN_BLOCKS; off <<= 1) {
        unsigned int x = (t >= off) ? sh[t - off] : 0u;
        __syncthreads();
        sh[t] += x;
        __syncthreads();
    }
    blocksums[t] = (t == 0) ? 0u : sh[t - 1];
}

// --- K4: globalize starts, copy to fill cursors, write sentinel ---
__global__ void fixup_kernel(unsigned int* __restrict__ starts,
                             unsigned int* __restrict__ cursors,
                             const unsigned int* __restrict__ blocksums)
{
    int t = blockIdx.x * blockDim.x + threadIdx.x;
    if (t >= N_CELLS) return;
    unsigned int g = starts[t] + blocksums[t >> 12];
    starts[t] = g;
    cursors[t] = g;
    if (t == 0) starts[N_CELLS] = (unsigned int)N_VOX;
}

// --- K5: fill CSR list ---
__global__ void fill_kernel(const int* __restrict__ coords,
                            unsigned int* __restrict__ cursors,
                            unsigned int* __restrict__ list)
{
    int n = blockIdx.x * blockDim.x + threadIdx.x;
    if (n >= N_VOX) return;
    int cx = coords[n * 3 + 0];
    int cy = coords[n * 3 + 1];
    int cz = coords[n * 3 + 2];
    int cid = (cx * RES + cy) * RES + cz;
    unsigned int slot = atomicAdd(cursors + cid, 1u);
    list[slot] = (unsigned int)n;
}

// --- K6: permute feats into cell-sorted, corner-SoA rows ---
// perm[slot*80 + c*10 + k] = {sdf_c, deform_c[0..2], color_c[0..5]} of voxel
// list[slot]. One wave per slot; lanes 0..39 copy 2 floats each (float2 write).
__global__ void permute_kernel(const float* __restrict__ feats,
                               const unsigned int* __restrict__ list,
                               float* __restrict__ perm)
{
    int tid = threadIdx.x;
    int slot = blockIdx.x * 4 + (tid >> 6);
    int lane = tid & 63;
    if (slot >= N_VOX || lane >= 40) return;
    long src = (long)list[slot] * 101;
    int d0 = lane * 2;
#pragma unroll
    for (int u = 0; u < 1; ++u) {}  // keep structure simple
    float vals[2];
#pragma unroll
    for (int u = 0; u < 2; ++u) {
        int d = d0 + u;
        int c = d / 10;
        int k = d - c * 10;
        int off = (k == 0) ? c : (k < 4 ? 8 + 3 * c + (k - 1) : 53 + 6 * c + (k - 4));
        vals[u] = feats[src + off];
    }
    *(float2*)(perm + (long)slot * 80 + d0) = make_float2(vals[0], vals[1]);
}

// --- K7: vertex-linear gather from permuted rows (40B contiguous per visit) ---
__global__ void gather_perm(const unsigned int* __restrict__ starts,
                            const float* __restrict__ perm,
                            float* __restrict__ vout)
{
    int vid = blockIdx.x * blockDim.x + threadIdx.x;
    if (vid >= N_VERTS) return;
    int z = vid % RES_V;
    int tmp = vid / RES_V;
    int y = tmp % RES_V;
    int x = tmp / RES_V;

    float sums[10];
#pragma unroll
    for (int j = 0; j < 10; ++j) sums[j] = 0.0f;
    int cnt = 0;

#pragma unroll
    for (int dx = 0; dx < 2; ++dx) {
        int cx = x - dx;
        if ((unsigned)cx >= RES) continue;
#pragma unroll
        for (int dy = 0; dy < 2; ++dy) {
            int cy = y - dy;
            if ((unsigned)cy >= RES) continue;
#pragma unroll
            for (int dz = 0; dz < 2; ++dz) {
                int cz = z - dz;
                if ((unsigned)cz >= RES) continue;
                int cid = (cx * RES + cy) * RES + cz;
                unsigned int s = starts[cid];
                unsigned int e = starts[cid + 1];
                if (s == e) continue;
                int c = dx + 2 * dy + 4 * dz;
                for (unsigned int i = s; i < e; ++i) {
                    const float* b = perm + (long)i * 80 + c * 10;
                    float2 p0 = *(const float2*)(b + 0);
                    float2 p1 = *(const float2*)(b + 2);
                    float2 p2 = *(const float2*)(b + 4);
                    float2 p3 = *(const float2*)(b + 6);
                    float2 p4 = *(const float2*)(b + 8);
                    sums[0] += p0.x; sums[1] += p0.y;
                    sums[2] += p1.x; sums[3] += p1.y;
                    sums[4] += p2.x; sums[5] += p2.y;
                    sums[6] += p3.x; sums[7] += p3.y;
                    sums[8] += p4.x; sums[9] += p4.y;
                }
                cnt += (int)(e - s);
            }
        }
    }

    float fc = (float)cnt;
    float inv = 1.0f / fmaxf(fc, 1.0f);
    float o[10];
    o[0] = (float)x * INV_RES - 0.5f + DEFORM_SCALE * tanhf(sums[1] * inv);
    o[1] = (float)y * INV_RES - 0.5f + DEFORM_SCALE * tanhf(sums[2] * inv);
    o[2] = (float)z * INV_RES - 0.5f + DEFORM_SCALE * tanhf(sums[3] * inv);
    o[3] = (sums[0] + fc * SDF_BIAS) * inv;
#pragma unroll
    for (int j = 0; j < 6; ++j) o[4 + j] = sums[4 + j] * inv;

    float* p = vout + (long)vid * 10;
#pragma unroll
    for (int j = 0; j < 5; ++j)
        *(float2*)(p + 2 * j) = make_float2(o[2 * j], o[2 * j + 1]);
}

// --- K8: weights grid; last-write-wins = max voxel id in the cell's CSR list ---
__global__ void weights_fill(const float* __restrict__ feats,
                             const unsigned int* __restrict__ starts,
                             const unsigned int* __restrict__ list,
                             float* __restrict__ outw)
{
    long t = (long)blockIdx.x * blockDim.x + threadIdx.x;
    if (t >= OUTW_WORDS) return;
    int cid = (int)(t / 21);
    int j = (int)(t - (long)cid * 21);
    unsigned int s = starts[cid], e = starts[cid + 1];
    float val = 0.0f;
    if (e > s) {
        unsigned int li = 0u;
        for (unsigned int i = s; i < e; ++i) li = max(li, list[i]);
        val = feats[(long)li * 101 + 32 + j];
    }
    outw[t] = val;
}

extern "C" void kernel_launch(void* const* d_in, const int* in_sizes, int n_in,
                              void* d_out, int out_size, void* d_ws, size_t ws_size,
                              hipStream_t stream) {
    const int* coords = (const int*)d_in[0];
    const float* feats = (const float*)d_in[1];
    float* out = (float*)d_out;
    float* vout = out;                          // [N_VERTS*10]
    float* outw = out + VOUT_WORDS;             // [N_CELLS*21]

    // d_ws (~10 MB): starts[N_CELLS+1], list[N_VOX], blocksums[512]
    unsigned int* starts = (unsigned int*)d_ws;
    unsigned int* list = starts + (N_CELLS + 1);
    unsigned int* blocksums = list + N_VOX;

    // In the outw region (all dead before weights_fill overwrites it):
    //   perm:   head, 400k*80 floats = 32,000,000 words (128 MB)
    //   counts: tail, N_CELLS words — disjoint from perm (41.9M > 32M)
    float* perm = outw;
    unsigned int* counts = (unsigned int*)(outw + (OUTW_WORDS - N_CELLS - 16));

    init_counts<<<(N_CELLS + 255) / 256, 256, 0, stream>>>(counts);
    count_kernel<<<(N_VOX + 255) / 256, 256, 0, stream>>>(coords, counts);
    scan1_kernel<<<SCAN_BLOCKS, 256, 0, stream>>>(counts, starts, blocksums);
    scan2_kernel<<<1, SCAN_BLOCKS, 0, stream>>>(blocksums);
    fixup_kernel<<<(N_CELLS + 255) / 256, 256, 0, stream>>>(starts, counts, blocksums);
    fill_kernel<<<(N_VOX + 255) / 256, 256, 0, stream>>>(coords, counts, list);
    permute_kernel<<<(N_VOX + 3) / 4, 256, 0, stream>>>(feats, list, perm);
    gather_perm<<<(N_VERTS + 255) / 256, 256, 0, stream>>>(starts, perm, vout);
    {
        long total = OUTW_WORDS;
        weights_fill<<<(int)((total + 255) / 256), 256, 0, stream>>>(feats, starts, list, outw);
    }
}

// Round 7
// 260.122 us; speedup vs baseline: 1.8667x; 1.5386x over previous
//
#include <hip/hip_runtime.h>

#define RES 128
#define RES_V 129
#define N_VOX 400000

constexpr int N_VERTS = RES_V * RES_V * RES_V;   // 2146689
constexpr int N_CELLS = RES * RES * RES;         // 2097152
constexpr long VOUT_WORDS = (long)N_VERTS * 10;  // 21466890
constexpr long OUTW_WORDS = (long)N_CELLS * 21;  // 44040192
constexpr int SCAN_BLOCKS = 512;                 // N_CELLS / 4096
constexpr float SDF_BIAS = -1.0f / 128.0f;
constexpr float DEFORM_SCALE = (float)((1.0 - 1e-8) / 256.0);
constexpr float INV_RES = 1.0f / 128.0f;

// --- K0: zero the cell histogram ---
__global__ void init_counts(unsigned int* __restrict__ counts)
{
    int t = blockIdx.x * blockDim.x + threadIdx.x;
    if (t < N_CELLS) counts[t] = 0u;
}

// --- K1: per-voxel cell histogram ---
__global__ void count_kernel(const int* __restrict__ coords,
                             unsigned int* __restrict__ counts)
{
    int n = blockIdx.x * blockDim.x + threadIdx.x;
    if (n >= N_VOX) return;
    int cx = coords[n * 3 + 0];
    int cy = coords[n * 3 + 1];
    int cz = coords[n * 3 + 2];
    int cid = (cx * RES + cy) * RES + cz;
    atomicAdd(counts + cid, 1u);
}

// --- K2: block-local exclusive scan (4096 elems / block) -> starts(local) ---
__global__ void scan1_kernel(const unsigned int* __restrict__ counts,
                             unsigned int* __restrict__ starts,
                             unsigned int* __restrict__ blocksums)
{
    __shared__ unsigned int part[256];
    int b = blockIdx.x, t = threadIdx.x;
    long base = (long)b * 4096 + (long)t * 16;
    unsigned int v[16], s = 0;
#pragma unroll
    for (int i = 0; i < 16; ++i) { v[i] = counts[base + i]; s += v[i]; }
    part[t] = s;
    __syncthreads();
    for (int off = 1; off < 256; off <<= 1) {
        unsigned int x = (t >= off) ? part[t - off] : 0u;
        __syncthreads();
        part[t] += x;
        __syncthreads();
    }
    unsigned int excl = (t == 0) ? 0u : part[t - 1];
    if (t == 255) blocksums[b] = part[255];
    unsigned int run = excl;
#pragma unroll
    for (int i = 0; i < 16; ++i) { starts[base + i] = run; run += v[i]; }
}

// --- K3: exclusive scan of the 512 block sums (single block) ---
__global__ void scan2_kernel(unsigned int* __restrict__ blocksums)
{
    __shared__ unsigned int sh[SCAN_BLOCKS];
    int t = threadIdx.x;
    sh[t] = blocksums[t];
    __syncthreads();
    for (int off = 1; off < SCAN_BLOCKS; off <<= 1) {
        unsigned int x = (t >= off) ? sh[t - off] : 0u;
        __syncthreads();
        sh[t] += x;
        __syncthreads();
    }
    blocksums[t] = (t == 0) ? 0u : sh[t - 1];
}

// --- K4: globalize starts, copy to fill cursors, write sentinel ---
__global__ void fixup_kernel(unsigned int* __restrict__ starts,
                             unsigned int* __restrict__ cursors,
                             const unsigned int* __restrict__ blocksums)
{
    int t = blockIdx.x * blockDim.x + threadIdx.x;
    if (t >= N_CELLS) return;
    unsigned int g = starts[t] + blocksums[t >> 12];
    starts[t] = g;
    cursors[t] = g;
    if (t == 0) starts[N_CELLS] = (unsigned int)N_VOX;
}

// --- K5: fill CSR list ---
__global__ void fill_kernel(const int* __restrict__ coords,
                            unsigned int* __restrict__ cursors,
                            unsigned int* __restrict__ list)
{
    int n = blockIdx.x * blockDim.x + threadIdx.x;
    if (n >= N_VOX) return;
    int cx = coords[n * 3 + 0];
    int cy = coords[n * 3 + 1];
    int cz = coords[n * 3 + 2];
    int cid = (cx * RES + cy) * RES + cz;
    unsigned int slot = atomicAdd(cursors + cid, 1u);
    list[slot] = (unsigned int)n;
}

// --- K6: permute feats into cell-sorted, corner-SoA rows ---
// 8 threads per slot; thread handles one corner c: 10 scalar reads from the
// voxel's feats row, one 40B contiguous write (5x float2, 8B-aligned).
__global__ void permute_kernel(const float* __restrict__ feats,
                               const unsigned int* __restrict__ list,
                               float* __restrict__ perm)
{
    int g = blockIdx.x * blockDim.x + threadIdx.x;
    int slot = g >> 3;
    int c = g & 7;
    if (slot >= N_VOX) return;
    long src = (long)list[slot] * 101;
    float v[10];
    v[0] = feats[src + c];
#pragma unroll
    for (int k = 0; k < 3; ++k) v[1 + k] = feats[src + 8 + 3 * c + k];
#pragma unroll
    for (int k = 0; k < 6; ++k) v[4 + k] = feats[src + 53 + 6 * c + k];
    float* d = perm + (long)slot * 80 + c * 10;
#pragma unroll
    for (int q = 0; q < 5; ++q)
        *(float2*)(d + 2 * q) = make_float2(v[2 * q], v[2 * q + 1]);
}

// --- K7: vertex-linear gather from permuted rows (40B contiguous per visit) ---
__global__ void gather_perm(const unsigned int* __restrict__ starts,
                            const float* __restrict__ perm,
                            float* __restrict__ vout)
{
    int vid = blockIdx.x * blockDim.x + threadIdx.x;
    if (vid >= N_VERTS) return;
    int z = vid % RES_V;
    int tmp = vid / RES_V;
    int y = tmp % RES_V;
    int x = tmp / RES_V;

    float sums[10];
#pragma unroll
    for (int j = 0; j < 10; ++j) sums[j] = 0.0f;
    int cnt = 0;

#pragma unroll
    for (int dx = 0; dx < 2; ++dx) {
        int cx = x - dx;
        if ((unsigned)cx >= RES) continue;
#pragma unroll
        for (int dy = 0; dy < 2; ++dy) {
            int cy = y - dy;
            if ((unsigned)cy >= RES) continue;
#pragma unroll
            for (int dz = 0; dz < 2; ++dz) {
                int cz = z - dz;
                if ((unsigned)cz >= RES) continue;
                int cid = (cx * RES + cy) * RES + cz;
                unsigned int s = starts[cid];
                unsigned int e = starts[cid + 1];
                if (s == e) continue;
                int c = dx + 2 * dy + 4 * dz;
                for (unsigned int i = s; i < e; ++i) {
                    const float* b = perm + (long)i * 80 + c * 10;
                    float2 p0 = *(const float2*)(b + 0);
                    float2 p1 = *(const float2*)(b + 2);
                    float2 p2 = *(const float2*)(b + 4);
                    float2 p3 = *(const float2*)(b + 6);
                    float2 p4 = *(const float2*)(b + 8);
                    sums[0] += p0.x; sums[1] += p0.y;
                    sums[2] += p1.x; sums[3] += p1.y;
                    sums[4] += p2.x; sums[5] += p2.y;
                    sums[6] += p3.x; sums[7] += p3.y;
                    sums[8] += p4.x; sums[9] += p4.y;
                }
                cnt += (int)(e - s);
            }
        }
    }

    float fc = (float)cnt;
    float inv = 1.0f / fmaxf(fc, 1.0f);
    float o[10];
    o[0] = (float)x * INV_RES - 0.5f + DEFORM_SCALE * tanhf(sums[1] * inv);
    o[1] = (float)y * INV_RES - 0.5f + DEFORM_SCALE * tanhf(sums[2] * inv);
    o[2] = (float)z * INV_RES - 0.5f + DEFORM_SCALE * tanhf(sums[3] * inv);
    o[3] = (sums[0] + fc * SDF_BIAS) * inv;
#pragma unroll
    for (int j = 0; j < 6; ++j) o[4 + j] = sums[4 + j] * inv;

    float* p = vout + (long)vid * 10;
#pragma unroll
    for (int j = 0; j < 5; ++j)
        *(float2*)(p + 2 * j) = make_float2(o[2 * j], o[2 * j + 1]);
}

// --- K8: weights grid, one thread per CELL; LDS transpose for coalesced
// stores. vals[t*21+j]: stride 21 coprime with 32 banks -> conflict-free. ---
__global__ void weights_fill2(const float* __restrict__ feats,
                              const unsigned int* __restrict__ starts,
                              const unsigned int* __restrict__ list,
                              float* __restrict__ outw)
{
    __shared__ float vals[256 * 21];
    int t = threadIdx.x;
    int cell0 = blockIdx.x * 256;
    int cell = cell0 + t;                 // N_CELLS = 8192*256 exactly

    unsigned int s = starts[cell];
    unsigned int e = starts[cell + 1];
    if (e > s) {
        unsigned int li = 0u;
        for (unsigned int i = s; i < e; ++i) li = max(li, list[i]);
        const float* f = feats + (long)li * 101 + 32;
#pragma unroll
        for (int j = 0; j < 21; ++j) vals[t * 21 + j] = f[j];
    } else {
#pragma unroll
        for (int j = 0; j < 21; ++j) vals[t * 21 + j] = 0.0f;
    }
    __syncthreads();

    float* dst = outw + (long)cell0 * 21;
#pragma unroll
    for (int k = 0; k < 21; ++k) dst[t + 256 * k] = vals[t + 256 * k];
}

extern "C" void kernel_launch(void* const* d_in, const int* in_sizes, int n_in,
                              void* d_out, int out_size, void* d_ws, size_t ws_size,
                              hipStream_t stream) {
    const int* coords = (const int*)d_in[0];
    const float* feats = (const float*)d_in[1];
    float* out = (float*)d_out;
    float* vout = out;                          // [N_VERTS*10]
    float* outw = out + VOUT_WORDS;             // [N_CELLS*21]

    // d_ws (~10 MB): starts[N_CELLS+1], list[N_VOX], blocksums[512]
    unsigned int* starts = (unsigned int*)d_ws;
    unsigned int* list = starts + (N_CELLS + 1);
    unsigned int* blocksums = list + N_VOX;

    // In the outw region (all dead before weights_fill2 overwrites it):
    //   perm:   head, 400k*80 floats = 32,000,000 words (128 MB)
    //   counts: tail, N_CELLS words — disjoint from perm (41.9M > 32M)
    float* perm = outw;
    unsigned int* counts = (unsigned int*)(outw + (OUTW_WORDS - N_CELLS - 16));

    init_counts<<<(N_CELLS + 255) / 256, 256, 0, stream>>>(counts);
    count_kernel<<<(N_VOX + 255) / 256, 256, 0, stream>>>(coords, counts);
    scan1_kernel<<<SCAN_BLOCKS, 256, 0, stream>>>(counts, starts, blocksums);
    scan2_kernel<<<1, SCAN_BLOCKS, 0, stream>>>(blocksums);
    fixup_kernel<<<(N_CELLS + 255) / 256, 256, 0, stream>>>(starts, counts, blocksums);
    fill_kernel<<<(N_VOX + 255) / 256, 256, 0, stream>>>(coords, counts, list);
    permute_kernel<<<(N_VOX * 8 + 255) / 256, 256, 0, stream>>>(feats, list, perm);
    gather_perm<<<(N_VERTS + 255) / 256, 256, 0, stream>>>(starts, perm, vout);
    weights_fill2<<<N_CELLS / 256, 256, 0, stream>>>(feats, starts, list, outw);
}

// Round 8
// 220.799 us; speedup vs baseline: 2.1992x; 1.1781x over previous
//
#include <hip/hip_runtime.h>

#define RES 128
#define RES_V 129
#define N_VOX 400000

constexpr int N_VERTS = RES_V * RES_V * RES_V;   // 2146689
constexpr int N_CELLS = RES * RES * RES;         // 2097152
constexpr long VOUT_WORDS = (long)N_VERTS * 10;  // 21466890
constexpr long OUTW_WORDS = (long)N_CELLS * 21;  // 44040192
constexpr int SCAN_BLOCKS = 512;                 // N_CELLS / 4096
constexpr float SDF_BIAS = -1.0f / 128.0f;
constexpr float DEFORM_SCALE = (float)((1.0 - 1e-8) / 256.0);
constexpr float INV_RES = 1.0f / 128.0f;

// bf16 pack/unpack (round-to-nearest-even)
static __device__ __forceinline__ unsigned int f2bf(float x) {
    unsigned int u = __float_as_uint(x);
    unsigned int r = ((u >> 16) & 1u) + 0x7FFFu;
    return (u + r) >> 16;
}
static __device__ __forceinline__ float bf_lo(unsigned int w) {
    return __uint_as_float(w << 16);
}
static __device__ __forceinline__ float bf_hi(unsigned int w) {
    return __uint_as_float(w & 0xFFFF0000u);
}

// --- K0: zero the cell histogram ---
__global__ void __launch_bounds__(256) init_counts(unsigned int* __restrict__ counts)
{
    int t = blockIdx.x * blockDim.x + threadIdx.x;
    if (t < N_CELLS) counts[t] = 0u;
}

// --- K1: per-voxel cell histogram ---
__global__ void __launch_bounds__(256) count_kernel(const int* __restrict__ coords,
                                                    unsigned int* __restrict__ counts)
{
    int n = blockIdx.x * blockDim.x + threadIdx.x;
    if (n >= N_VOX) return;
    int cx = coords[n * 3 + 0];
    int cy = coords[n * 3 + 1];
    int cz = coords[n * 3 + 2];
    int cid = (cx * RES + cy) * RES + cz;
    atomicAdd(counts + cid, 1u);
}

// --- K2: block-local exclusive scan (4096 elems / block) -> starts(local) ---
__global__ void __launch_bounds__(256) scan1_kernel(const unsigned int* __restrict__ counts,
                                                    unsigned int* __restrict__ starts,
                                                    unsigned int* __restrict__ blocksums)
{
    __shared__ unsigned int part[256];
    int b = blockIdx.x, t = threadIdx.x;
    long base = (long)b * 4096 + (long)t * 16;
    unsigned int v[16], s = 0;
#pragma unroll
    for (int i = 0; i < 16; ++i) { v[i] = counts[base + i]; s += v[i]; }
    part[t] = s;
    __syncthreads();
    for (int off = 1; off < 256; off <<= 1) {
        unsigned int x = (t >= off) ? part[t - off] : 0u;
        __syncthreads();
        part[t] += x;
        __syncthreads();
    }
    unsigned int excl = (t == 0) ? 0u : part[t - 1];
    if (t == 255) blocksums[b] = part[255];
    unsigned int run = excl;
#pragma unroll
    for (int i = 0; i < 16; ++i) { starts[base + i] = run; run += v[i]; }
}

// --- K3: exclusive scan of the 512 block sums (single block) ---
__global__ void __launch_bounds__(512) scan2_kernel(unsigned int* __restrict__ blocksums)
{
    __shared__ unsigned int sh[SCAN_BLOCKS];
    int t = threadIdx.x;
    sh[t] = blocksums[t];
    __syncthreads();
    for (int off = 1; off < SCAN_BLOCKS; off <<= 1) {
        unsigned int x = (t >= off) ? sh[t - off] : 0u;
        __syncthreads();
        sh[t] += x;
        __syncthreads();
    }
    blocksums[t] = (t == 0) ? 0u : sh[t - 1];
}

// --- K4: globalize starts, copy to fill cursors, write sentinel ---
__global__ void __launch_bounds__(256) fixup_kernel(unsigned int* __restrict__ starts,
                                                    unsigned int* __restrict__ cursors,
                                                    const unsigned int* __restrict__ blocksums)
{
    int t = blockIdx.x * blockDim.x + threadIdx.x;
    if (t >= N_CELLS) return;
    unsigned int g = starts[t] + blocksums[t >> 12];
    starts[t] = g;
    cursors[t] = g;
    if (t == 0) starts[N_CELLS] = (unsigned int)N_VOX;
}

// --- K5: fill CSR list ---
__global__ void __launch_bounds__(256) fill_kernel(const int* __restrict__ coords,
                                                   unsigned int* __restrict__ cursors,
                                                   unsigned int* __restrict__ list)
{
    int n = blockIdx.x * blockDim.x + threadIdx.x;
    if (n >= N_VOX) return;
    int cx = coords[n * 3 + 0];
    int cy = coords[n * 3 + 1];
    int cz = coords[n * 3 + 2];
    int cid = (cx * RES + cy) * RES + cz;
    unsigned int slot = atomicAdd(cursors + cid, 1u);
    list[slot] = (unsigned int)n;
}

// --- K6: permute feats into cell-sorted, corner-SoA bf16 rows ---
// 8 threads per slot; thread c packs its corner's 10 floats into 5 uints
// (2 bf16 each) at perm[slot*40 + c*5 .. +5).
__global__ void __launch_bounds__(256) permute_kernel(const float* __restrict__ feats,
                                                      const unsigned int* __restrict__ list,
                                                      unsigned int* __restrict__ perm)
{
    int g = blockIdx.x * blockDim.x + threadIdx.x;
    int slot = g >> 3;
    int c = g & 7;
    if (slot >= N_VOX) return;
    long src = (long)list[slot] * 101;
    float v[10];
    v[0] = feats[src + c];
#pragma unroll
    for (int k = 0; k < 3; ++k) v[1 + k] = feats[src + 8 + 3 * c + k];
#pragma unroll
    for (int k = 0; k < 6; ++k) v[4 + k] = feats[src + 53 + 6 * c + k];
    unsigned int* d = perm + (long)slot * 40 + c * 5;
#pragma unroll
    for (int q = 0; q < 5; ++q)
        d[q] = f2bf(v[2 * q]) | (f2bf(v[2 * q + 1]) << 16);
}

// --- K7: vertex-linear gather from permuted bf16 rows (20B per visit) ---
__global__ void __launch_bounds__(256) gather_perm(const unsigned int* __restrict__ starts,
                                                   const unsigned int* __restrict__ perm,
                                                   float* __restrict__ vout)
{
    int vid = blockIdx.x * blockDim.x + threadIdx.x;
    if (vid >= N_VERTS) return;
    int z = vid % RES_V;
    int tmp = vid / RES_V;
    int y = tmp % RES_V;
    int x = tmp / RES_V;

    float sums[10];
#pragma unroll
    for (int j = 0; j < 10; ++j) sums[j] = 0.0f;
    int cnt = 0;

#pragma unroll
    for (int dx = 0; dx < 2; ++dx) {
        int cx = x - dx;
        if ((unsigned)cx >= RES) continue;
#pragma unroll
        for (int dy = 0; dy < 2; ++dy) {
            int cy = y - dy;
            if ((unsigned)cy >= RES) continue;
#pragma unroll
            for (int dz = 0; dz < 2; ++dz) {
                int cz = z - dz;
                if ((unsigned)cz >= RES) continue;
                int cid = (cx * RES + cy) * RES + cz;
                unsigned int s = starts[cid];
                unsigned int e = starts[cid + 1];
                if (s == e) continue;
                int c = dx + 2 * dy + 4 * dz;
                for (unsigned int i = s; i < e; ++i) {
                    const unsigned int* b = perm + (long)i * 40 + c * 5;
                    unsigned int w0 = b[0], w1 = b[1], w2 = b[2], w3 = b[3], w4 = b[4];
                    sums[0] += bf_lo(w0); sums[1] += bf_hi(w0);
                    sums[2] += bf_lo(w1); sums[3] += bf_hi(w1);
                    sums[4] += bf_lo(w2); sums[5] += bf_hi(w2);
                    sums[6] += bf_lo(w3); sums[7] += bf_hi(w3);
                    sums[8] += bf_lo(w4); sums[9] += bf_hi(w4);
                }
                cnt += (int)(e - s);
            }
        }
    }

    float fc = (float)cnt;
    float inv = 1.0f / fmaxf(fc, 1.0f);
    float o[10];
    o[0] = (float)x * INV_RES - 0.5f + DEFORM_SCALE * tanhf(sums[1] * inv);
    o[1] = (float)y * INV_RES - 0.5f + DEFORM_SCALE * tanhf(sums[2] * inv);
    o[2] = (float)z * INV_RES - 0.5f + DEFORM_SCALE * tanhf(sums[3] * inv);
    o[3] = (sums[0] + fc * SDF_BIAS) * inv;
#pragma unroll
    for (int j = 0; j < 6; ++j) o[4 + j] = sums[4 + j] * inv;

    float* p = vout + (long)vid * 10;
#pragma unroll
    for (int j = 0; j < 5; ++j)
        *(float2*)(p + 2 * j) = make_float2(o[2 * j], o[2 * j + 1]);
}

// --- K8: weights grid, one thread per CELL; LDS transpose for coalesced
// stores. vals[t*21+j]: stride 21 coprime with 32 banks -> conflict-free. ---
__global__ void __launch_bounds__(256) weights_fill2(const float* __restrict__ feats,
                                                     const unsigned int* __restrict__ starts,
                                                     const unsigned int* __restrict__ list,
                                                     float* __restrict__ outw)
{
    __shared__ float vals[256 * 21];
    int t = threadIdx.x;
    int cell0 = blockIdx.x * 256;
    int cell = cell0 + t;                 // N_CELLS = 8192*256 exactly

    unsigned int s = starts[cell];
    unsigned int e = starts[cell + 1];
    if (e > s) {
        unsigned int li = 0u;
        for (unsigned int i = s; i < e; ++i) li = max(li, list[i]);
        const float* f = feats + (long)li * 101 + 32;
#pragma unroll
        for (int j = 0; j < 21; ++j) vals[t * 21 + j] = f[j];
    } else {
#pragma unroll
        for (int j = 0; j < 21; ++j) vals[t * 21 + j] = 0.0f;
    }
    __syncthreads();

    float* dst = outw + (long)cell0 * 21;
#pragma unroll
    for (int k = 0; k < 21; ++k) dst[t + 256 * k] = vals[t + 256 * k];
}

extern "C" void kernel_launch(void* const* d_in, const int* in_sizes, int n_in,
                              void* d_out, int out_size, void* d_ws, size_t ws_size,
                              hipStream_t stream) {
    const int* coords = (const int*)d_in[0];
    const float* feats = (const float*)d_in[1];
    float* out = (float*)d_out;
    float* vout = out;                          // [N_VERTS*10]
    float* outw = out + VOUT_WORDS;             // [N_CELLS*21]

    // d_ws (~10 MB): starts[N_CELLS+1], list[N_VOX], blocksums[512]
    unsigned int* starts = (unsigned int*)d_ws;
    unsigned int* list = starts + (N_CELLS + 1);
    unsigned int* blocksums = list + N_VOX;

    // In the outw region (all dead before weights_fill2 overwrites it):
    //   perm:   head, 400k*40 uints = 16,000,000 words (64 MB)
    //   counts: tail, N_CELLS words — disjoint from perm
    unsigned int* perm = (unsigned int*)outw;
    unsigned int* counts = (unsigned int*)(outw + (OUTW_WORDS - N_CELLS - 16));

    init_counts<<<(N_CELLS + 255) / 256, 256, 0, stream>>>(counts);
    count_kernel<<<(N_VOX + 255) / 256, 256, 0, stream>>>(coords, counts);
    scan1_kernel<<<SCAN_BLOCKS, 256, 0, stream>>>(counts, starts, blocksums);
    scan2_kernel<<<1, SCAN_BLOCKS, 0, stream>>>(blocksums);
    fixup_kernel<<<(N_CELLS + 255) / 256, 256, 0, stream>>>(starts, counts, blocksums);
    fill_kernel<<<(N_VOX + 255) / 256, 256, 0, stream>>>(coords, counts, list);
    permute_kernel<<<(N_VOX * 8 + 255) / 256, 256, 0, stream>>>(feats, list, perm);
    gather_perm<<<(N_VERTS + 255) / 256, 256, 0, stream>>>(starts, perm, vout);
    weights_fill2<<<N_CELLS / 256, 256, 0, stream>>>(feats, starts, list, outw);
}